// Round 1
// baseline (16166.672 us; speedup 1.0000x reference)
//
#include <hip/hip_runtime.h>
#include <hip/hip_bf16.h>

// ResNetTTT: fp32 correctness-first implementation.
// B=4, L=1024, D=256, H=4, dh=64, MB=4, 256 sequential TTT steps per (b,h).

#define ERF_CF 0.70710678118654752f
#define PDF_CF 0.3989422804014327f
#define ETA 0.025f   // TTT_LR / MB = 0.1/4

__device__ __forceinline__ float wsum(float v) {
#pragma unroll
  for (int o = 32; o > 0; o >>= 1) v += __shfl_xor(v, o, 64);
  return v;
}

// ---------------------------------------------------------------------------
// prep: transpose conv weights into GEMM-friendly [k][co] layout
// wt1[ci*256+co] = conv1_w[co*64+ci]
// wt[cv][ (t*256+ci)*256 + co ] = convs_w[cv][co][ci][t]
// ---------------------------------------------------------------------------
__global__ void prep_w(const float* __restrict__ c1w, const float* __restrict__ cw,
                       float* __restrict__ wt1, float* __restrict__ wt) {
  int id = blockIdx.x * 256 + threadIdx.x;
  if (id < 16384) {
    int ci = id >> 8, co = id & 255;
    wt1[id] = c1w[co * 64 + ci];
  }
  int id2 = id - 16384;
  if (id2 >= 0 && id2 < 1572864) {
    int cv = id2 / 196608;
    int r = id2 - cv * 196608;
    int k = r >> 8, co = r & 255;
    int tt = k >> 8, ci = k & 255;
    wt[id2] = cw[((cv * 256 + co) * 256 + ci) * 3 + tt];
  }
}

// zero the halo rows (row 0 and row 1025 per batch) of both ping-pong buffers
__global__ void zero_halo(float* __restrict__ bufA, float* __restrict__ bufB) {
  int id = blockIdx.x * 256 + threadIdx.x;  // 0..4095
  int c = id & 255;
  int row = (id >> 8) & 1;
  int b = (id >> 9) & 3;
  float* p = (id >> 11) ? bufB : bufA;
  p[(b * 1026 + row * 1025) * 256 + c] = 0.0f;
}

// ---------------------------------------------------------------------------
// Generic tiled fp32 GEMM: C[M,N] = A[M,K] @ Wt[K,N]  (Wt row-major [k][n])
// BM=BN=64, BK=16, 256 threads, 4x4 microtile.
// haloA: A row base = m*lda + (m>>10)*512  (conv halo addressing)
// OST: 0 plain out[m*N+n]; 1 halo store (conv activations, ldc=256);
//      2 qkv scatter into (B,H,L,64)
// ACC: 0 none; 1 store into accp[m*256+n]; 2 add into accp
// ---------------------------------------------------------------------------
template <int BIAS, int RELU, int RES, int OST, int ACC>
__global__ __launch_bounds__(256) void gemm_k(
    const float* __restrict__ A, const float* __restrict__ Wt,
    const float* __restrict__ bias, const float* __restrict__ res,
    float* __restrict__ out, float* __restrict__ accp,
    int M, int N, int K, int lda, int haloA) {
  __shared__ float As[16][68];
  __shared__ float Bs[16][64];
  const int tid = threadIdx.x;
  const int bm = blockIdx.x * 64, bn = blockIdx.y * 64;
  const int tx = tid & 15, ty = tid >> 4;
  float acc[4][4] = {};

  for (int k0 = 0; k0 < K; k0 += 16) {
#pragma unroll
    for (int i = 0; i < 4; ++i) {
      int idx = tid + i * 256;
      int kk = idx & 15, mm = idx >> 4;
      int m = bm + mm;
      int rb = m * lda + (haloA ? ((m >> 10) << 9) : 0);
      As[kk][mm] = A[rb + k0 + kk];
    }
#pragma unroll
    for (int i = 0; i < 4; ++i) {
      int idx = tid + i * 256;
      int nn = idx & 63, kk = idx >> 6;
      Bs[kk][nn] = Wt[(k0 + kk) * N + bn + nn];
    }
    __syncthreads();
#pragma unroll
    for (int kk = 0; kk < 16; ++kk) {
      float4 av = *(const float4*)&As[kk][ty * 4];
      float4 bv = *(const float4*)&Bs[kk][tx * 4];
      float aa[4] = {av.x, av.y, av.z, av.w};
      float bb[4] = {bv.x, bv.y, bv.z, bv.w};
#pragma unroll
      for (int i = 0; i < 4; ++i)
#pragma unroll
        for (int j = 0; j < 4; ++j) acc[i][j] = fmaf(aa[i], bb[j], acc[i][j]);
    }
    __syncthreads();
  }

  const int n0 = bn + tx * 4;
#pragma unroll
  for (int i = 0; i < 4; ++i) {
    int m = bm + ty * 4 + i;
    int b_ = m >> 10, l = m & 1023;
    float v[4];
#pragma unroll
    for (int j = 0; j < 4; ++j) {
      float x = acc[i][j];
      if constexpr (BIAS) x += bias[n0 + j];
      if constexpr (RELU) x = fmaxf(x, 0.0f);
      if constexpr (RES) x += res[m * N + n0 + j];
      v[j] = x;
    }
    float4 vv = make_float4(v[0], v[1], v[2], v[3]);
    if constexpr (OST == 0) {
      *(float4*)&out[m * N + n0] = vv;
    } else if constexpr (OST == 1) {
      *(float4*)&out[(b_ * 1026 + l + 1) * 256 + n0] = vv;
    } else {
      int hq = n0 >> 6;
      int oidx = (((b_ * 4 + hq) * 1024 + l) << 6) + (n0 & 63);
      *(float4*)&out[oidx] = vv;
    }
    if constexpr (ACC == 1) {
      *(float4*)&accp[m * 256 + n0] = vv;
    } else if constexpr (ACC == 2) {
      float4 s = *(const float4*)&accp[m * 256 + n0];
      s.x += vv.x; s.y += vv.y; s.z += vv.z; s.w += vv.w;
      *(float4*)&accp[m * 256 + n0] = s;
    }
  }
}

// ---------------------------------------------------------------------------
// LayerNorm over last dim (256), rows contiguous. 64 threads = 1 wave per row.
// ---------------------------------------------------------------------------
__global__ __launch_bounds__(64) void ln_kernel(const float* __restrict__ in,
                                                float* __restrict__ o,
                                                const float* __restrict__ w,
                                                const float* __restrict__ bb,
                                                float eps) {
  int row = blockIdx.x;
  int l = threadIdx.x;
  float4 v = ((const float4*)(in + (long)row * 256))[l];
  float s = wsum(v.x + v.y + v.z + v.w);
  float mu = s * (1.0f / 256.0f);
  float dx = v.x - mu, dy = v.y - mu, dz = v.z - mu, dw = v.w - mu;
  float ss = wsum(dx * dx + dy * dy + dz * dz + dw * dw);
  float rstd = rsqrtf(ss * (1.0f / 256.0f) + eps);
  float4 wv = ((const float4*)w)[l];
  float4 bv = ((const float4*)bb)[l];
  float4 r;
  r.x = wv.x * dx * rstd + bv.x;
  r.y = wv.y * dy * rstd + bv.y;
  r.z = wv.z * dz * rstd + bv.z;
  r.w = wv.w * dw * rstd + bv.w;
  ((float4*)(o + (long)row * 256))[l] = r;
}

// ---------------------------------------------------------------------------
// TTT scan: one block per (b,h) chain. 256 threads (4 waves).
// Registers: w1[64] = W1 column t; w2row[64] = W2 row t; w2col[64] = W2[r0+kk][lane].
// LDS holds only the 4x64 mini-batch tensors + small scratch.
// ---------------------------------------------------------------------------
__global__ __launch_bounds__(256, 1) void ttt_kernel(
    const float* __restrict__ XQ, const float* __restrict__ XK,
    const float* __restrict__ XV, const float* __restrict__ W1i,
    const float* __restrict__ B1i, const float* __restrict__ W2i,
    const float* __restrict__ B2i, const float* __restrict__ LNW,
    const float* __restrict__ LNB, float* __restrict__ outp) {
  const int bh = blockIdx.x;
  const int b = bh >> 2, h = bh & 3;
  const int t = threadIdx.x;
  const int w = t >> 6, lane = t & 63;
  const int r0 = w << 6;

  __shared__ float xkL[256], xvL[256], xqL[256];
  __shared__ float X2s[4][256];
  __shared__ float gZ2s[4][64];
  __shared__ float redS[4][4][64];
  __shared__ float b2s[64], lwS[64], lbS[64];

  float w1[64], w2row[64], w2col[64];
#pragma unroll
  for (int k = 0; k < 64; ++k) w1[k] = W1i[(h * 64 + k) * 256 + t];
  float b1r = B1i[h * 256 + t];
#pragma unroll
  for (int j = 0; j < 64; ++j) w2row[j] = W2i[(h * 256 + t) * 64 + j];
#pragma unroll
  for (int k = 0; k < 64; ++k) w2col[k] = W2i[(h * 256 + r0 + k) * 64 + lane];
  if (t < 64) {
    b2s[t] = B2i[h * 64 + t];
    lwS[t] = LNW[h * 64 + t];
    lbS[t] = LNB[h * 64 + t];
  }
  __syncthreads();

  const long chain = (long)bh * 1024 * 64;
  for (int n = 0; n < 256; ++n) {
    const long base = chain + (long)n * 256;
    xkL[t] = XK[base + t];
    xvL[t] = XV[base + t];
    xqL[t] = XQ[base + t];
    __syncthreads();  // B1

    // ---- Stage A: Z1 = xk@W1 + b1 ; X2 = gelu(Z1) ----
    float am[4];
    am[0] = am[1] = am[2] = am[3] = b1r;
#pragma unroll
    for (int k4 = 0; k4 < 64; k4 += 4) {
      float4 xx[4];
      xx[0] = *(const float4*)&xkL[k4];
      xx[1] = *(const float4*)&xkL[64 + k4];
      xx[2] = *(const float4*)&xkL[128 + k4];
      xx[3] = *(const float4*)&xkL[192 + k4];
#pragma unroll
      for (int m = 0; m < 4; ++m) {
        am[m] = fmaf(xx[m].x, w1[k4], am[m]);
        am[m] = fmaf(xx[m].y, w1[k4 + 1], am[m]);
        am[m] = fmaf(xx[m].z, w1[k4 + 2], am[m]);
        am[m] = fmaf(xx[m].w, w1[k4 + 3], am[m]);
      }
    }
    float z1r[4], er[4], x2r[4];
#pragma unroll
    for (int m = 0; m < 4; ++m) {
      float z = am[m];
      z1r[m] = z;
      er[m] = erff(z * ERF_CF);
      float g = 0.5f * z * (1.0f + er[m]);
      x2r[m] = g;
      X2s[m][t] = g;
    }
    __syncthreads();  // B2

    // ---- Stage B partial: Z2 partial over k2 in [r0, r0+64) for column lane ----
    float pp[4] = {0, 0, 0, 0};
#pragma unroll
    for (int k4 = 0; k4 < 64; k4 += 4) {
      float4 yy[4];
      yy[0] = *(const float4*)&X2s[0][r0 + k4];
      yy[1] = *(const float4*)&X2s[1][r0 + k4];
      yy[2] = *(const float4*)&X2s[2][r0 + k4];
      yy[3] = *(const float4*)&X2s[3][r0 + k4];
#define BP(J, C)                                    \
  {                                                 \
    float wv = w2col[k4 + J];                       \
    pp[0] = fmaf(yy[0].C, wv, pp[0]);               \
    pp[1] = fmaf(yy[1].C, wv, pp[1]);               \
    pp[2] = fmaf(yy[2].C, wv, pp[2]);               \
    pp[3] = fmaf(yy[3].C, wv, pp[3]);               \
  }
      BP(0, x) BP(1, y) BP(2, z) BP(3, w)
#undef BP
    }
    redS[w][0][lane] = pp[0];
    redS[w][1][lane] = pp[1];
    redS[w][2][lane] = pp[2];
    redS[w][3][lane] = pp[3];
    __syncthreads();  // B3

    // ---- Stage B-reduce + C: LN-l2-bwd. mapping: row m = w, col j2 = lane ----
    {
      float z2 = b2s[lane] + redS[0][w][lane] + redS[1][w][lane] +
                 redS[2][w][lane] + redS[3][w][lane];
      float mu = wsum(z2) * (1.0f / 64.0f);
      float dv = z2 - mu;
      float var = wsum(dv * dv) * (1.0f / 64.0f);
      float stdv = sqrtf(var + 1e-6f);
      float zhat = dv / stdv;
      float lwv = lwS[lane], lbv = lbS[lane];
      float tgt = xvL[r0 + lane] - xkL[r0 + lane];
      float g = lwv * (lwv * zhat + lbv - tgt);
      float gs = wsum(g) * (1.0f / 64.0f);
      float gzs = wsum(g * zhat) * (1.0f / 64.0f);
      gZ2s[w][lane] = (g - gs - zhat * gzs) / stdv;
    }
    __syncthreads();  // B4

    // ---- Stage D (gZ1 = gZ2@W2^T * gelu') fused with w2row update ----
    float sD[4] = {0, 0, 0, 0};
#pragma unroll
    for (int p4 = 0; p4 < 64; p4 += 4) {
      float4 gg[4];
      gg[0] = *(const float4*)&gZ2s[0][p4];
      gg[1] = *(const float4*)&gZ2s[1][p4];
      gg[2] = *(const float4*)&gZ2s[2][p4];
      gg[3] = *(const float4*)&gZ2s[3][p4];
#define DE(J, C)                                                            \
  {                                                                         \
    float wv = w2row[p4 + J];                                               \
    sD[0] = fmaf(gg[0].C, wv, sD[0]);                                       \
    sD[1] = fmaf(gg[1].C, wv, sD[1]);                                       \
    sD[2] = fmaf(gg[2].C, wv, sD[2]);                                       \
    sD[3] = fmaf(gg[3].C, wv, sD[3]);                                       \
    float u = x2r[0] * gg[0].C;                                             \
    u = fmaf(x2r[1], gg[1].C, u);                                           \
    u = fmaf(x2r[2], gg[2].C, u);                                           \
    u = fmaf(x2r[3], gg[3].C, u);                                           \
    w2row[p4 + J] = fmaf(-ETA, u, wv);                                      \
  }
      DE(0, x) DE(1, y) DE(2, z) DE(3, w)
#undef DE
    }
    float gz1[4];
#pragma unroll
    for (int m = 0; m < 4; ++m) {
      float z = z1r[m];
      float gg = 0.5f * (1.0f + er[m]) + z * expf(-0.5f * z * z) * PDF_CF;
      gz1[m] = sD[m] * gg;
    }

    // ---- Stage E: W1 (column t) + b1 update ----
#pragma unroll
    for (int k4 = 0; k4 < 64; k4 += 4) {
      float4 xx[4];
      xx[0] = *(const float4*)&xkL[k4];
      xx[1] = *(const float4*)&xkL[64 + k4];
      xx[2] = *(const float4*)&xkL[128 + k4];
      xx[3] = *(const float4*)&xkL[192 + k4];
#define W1U(J, C)                                                           \
  {                                                                         \
    float u = xx[0].C * gz1[0];                                             \
    u = fmaf(xx[1].C, gz1[1], u);                                           \
    u = fmaf(xx[2].C, gz1[2], u);                                           \
    u = fmaf(xx[3].C, gz1[3], u);                                           \
    w1[k4 + J] = fmaf(-ETA, u, w1[k4 + J]);                                 \
  }
      W1U(0, x) W1U(1, y) W1U(2, z) W1U(3, w)
#undef W1U
    }
    b1r = fmaf(-ETA, gz1[0] + gz1[1] + gz1[2] + gz1[3], b1r);

    // ---- Stage E: w2col update ----
    {
      float go[4] = {gZ2s[0][lane], gZ2s[1][lane], gZ2s[2][lane], gZ2s[3][lane]};
#pragma unroll
      for (int k4 = 0; k4 < 64; k4 += 4) {
        float4 yy[4];
        yy[0] = *(const float4*)&X2s[0][r0 + k4];
        yy[1] = *(const float4*)&X2s[1][r0 + k4];
        yy[2] = *(const float4*)&X2s[2][r0 + k4];
        yy[3] = *(const float4*)&X2s[3][r0 + k4];
#define W2U(J, C)                                                           \
  {                                                                         \
    float u = yy[0].C * go[0];                                              \
    u = fmaf(yy[1].C, go[1], u);                                            \
    u = fmaf(yy[2].C, go[2], u);                                            \
    u = fmaf(yy[3].C, go[3], u);                                            \
    w2col[k4 + J] = fmaf(-ETA, u, w2col[k4 + J]);                           \
  }
        W2U(0, x) W2U(1, y) W2U(2, z) W2U(3, w)
#undef W2U
      }
    }
    // b2 update (wave 0): safe — last b2s read was before B4
    if (t < 64) {
      float gb = gZ2s[0][t] + gZ2s[1][t] + gZ2s[2][t] + gZ2s[3][t];
      b2s[t] = fmaf(-ETA, gb, b2s[t]);
    }
    __syncthreads();  // B5: all reads of X2s/gZ2s done

    // ---- Stage F: Z1q = xq@W1n + b1n ; X2q = gelu -> X2s ----
    am[0] = am[1] = am[2] = am[3] = b1r;
#pragma unroll
    for (int k4 = 0; k4 < 64; k4 += 4) {
      float4 xx[4];
      xx[0] = *(const float4*)&xqL[k4];
      xx[1] = *(const float4*)&xqL[64 + k4];
      xx[2] = *(const float4*)&xqL[128 + k4];
      xx[3] = *(const float4*)&xqL[192 + k4];
#pragma unroll
      for (int m = 0; m < 4; ++m) {
        am[m] = fmaf(xx[m].x, w1[k4], am[m]);
        am[m] = fmaf(xx[m].y, w1[k4 + 1], am[m]);
        am[m] = fmaf(xx[m].z, w1[k4 + 2], am[m]);
        am[m] = fmaf(xx[m].w, w1[k4 + 3], am[m]);
      }
    }
#pragma unroll
    for (int m = 0; m < 4; ++m) {
      float z = am[m];
      X2s[m][t] = 0.5f * z * (1.0f + erff(z * ERF_CF));
    }
    __syncthreads();  // B6

    // ---- Stage G partial: Z2q partials (uses updated w2col) ----
    pp[0] = pp[1] = pp[2] = pp[3] = 0.0f;
#pragma unroll
    for (int k4 = 0; k4 < 64; k4 += 4) {
      float4 yy[4];
      yy[0] = *(const float4*)&X2s[0][r0 + k4];
      yy[1] = *(const float4*)&X2s[1][r0 + k4];
      yy[2] = *(const float4*)&X2s[2][r0 + k4];
      yy[3] = *(const float4*)&X2s[3][r0 + k4];
#define GP(J, C)                                    \
  {                                                 \
    float wv = w2col[k4 + J];                       \
    pp[0] = fmaf(yy[0].C, wv, pp[0]);               \
    pp[1] = fmaf(yy[1].C, wv, pp[1]);               \
    pp[2] = fmaf(yy[2].C, wv, pp[2]);               \
    pp[3] = fmaf(yy[3].C, wv, pp[3]);               \
  }
      GP(0, x) GP(1, y) GP(2, z) GP(3, w)
#undef GP
    }
    redS[w][0][lane] = pp[0];
    redS[w][1][lane] = pp[1];
    redS[w][2][lane] = pp[2];
    redS[w][3][lane] = pp[3];
    __syncthreads();  // B7

    // ---- Stage G reduce + LN fwd + output ----
    {
      float z2 = b2s[lane] + redS[0][w][lane] + redS[1][w][lane] +
                 redS[2][w][lane] + redS[3][w][lane];
      float mu = wsum(z2) * (1.0f / 64.0f);
      float dv = z2 - mu;
      float var = wsum(dv * dv) * (1.0f / 64.0f);
      float rstd = rsqrtf(var + 1e-6f);
      float val = lwS[lane] * dv * rstd + lbS[lane] + xqL[r0 + lane];
      outp[((long)(b * 1024 + n * 4 + w)) * 256 + h * 64 + lane] = val;
    }
    __syncthreads();  // B8
  }
}

// final (4096,64) @ (64,1) + b
__global__ __launch_bounds__(256) void fc3_kernel(const float* __restrict__ f2,
                                                  const float* __restrict__ w,
                                                  const float* __restrict__ bias,
                                                  float* __restrict__ o) {
  int m = blockIdx.x * 4 + (threadIdx.x >> 6);
  int lane = threadIdx.x & 63;
  float v = f2[m * 64 + lane] * w[lane];
  v = wsum(v);
  if (lane == 0) o[m] = v + bias[0];
}

// ---------------------------------------------------------------------------
extern "C" void kernel_launch(void* const* d_in, const int* in_sizes, int n_in,
                              void* d_out, int out_size, void* d_ws, size_t ws_size,
                              hipStream_t stream) {
  const float* x       = (const float*)d_in[0];
  const float* conv1_w = (const float*)d_in[1];
  const float* conv1_b = (const float*)d_in[2];
  const float* convs_w = (const float*)d_in[3];
  const float* convs_b = (const float*)d_in[4];
  const float* ln_w    = (const float*)d_in[5];
  const float* ln_b    = (const float*)d_in[6];
  const float* wq      = (const float*)d_in[7];
  const float* wk      = (const float*)d_in[8];
  const float* wv      = (const float*)d_in[9];
  const float* wo      = (const float*)d_in[10];
  const float* ttt_W1  = (const float*)d_in[11];
  const float* ttt_b1  = (const float*)d_in[12];
  const float* ttt_W2  = (const float*)d_in[13];
  const float* ttt_b2  = (const float*)d_in[14];
  const float* ttt_lnw = (const float*)d_in[15];
  const float* ttt_lnb = (const float*)d_in[16];
  const float* fc_w    = (const float*)d_in[17];
  const float* fc_b    = (const float*)d_in[18];
  const float* fc2_w   = (const float*)d_in[19];
  const float* fc2_b   = (const float*)d_in[20];
  const float* fc3_w   = (const float*)d_in[21];
  const float* fc3_b   = (const float*)d_in[22];

  float* ws = (float*)d_ws;
  float* wt1  = ws + 0;                       // 16384
  float* wt   = ws + 16384;                   // 1572864
  float* bufA = ws + 1589248;                 // 1050624 (B,L+2,256)
  float* bufB = ws + 2639872;                 // 1050624
  float* sum4 = ws + 3690496;                 // 1048576 (B,L,256)
  float* tln  = ws + 4739072;                 // 1048576
  float* XQ   = ws + 5787648;                 // 1048576 (B,H,L,64)
  float* XK   = ws + 6836224;                 // 1048576
  float* XV   = ws + 7884800;                 // 1048576
  float* tout = ws + 8933376;                 // 1048576
  float* tfull = sum4;                        // reuse (free after first LN)
  float* h2    = bufA;                        // reuse (free after convs)
  float* f1    = XQ;                          // reuse (free after TTT), 2097152
  float* f2    = tout;                        // reuse (free after wo-GEMM)

  const int M = 4096;
  dim3 blk(256);

  zero_halo<<<16, blk, 0, stream>>>(bufA, bufB);
  prep_w<<<6208, blk, 0, stream>>>(conv1_w, convs_w, wt1, wt);

  // conv1 (1x1) + relu -> bufA (halo store)
  gemm_k<1, 1, 0, 1, 0><<<dim3(64, 4), blk, 0, stream>>>(
      x, wt1, conv1_b, nullptr, bufA, nullptr, M, 256, 64, 64, 0);

  // 8 sequential 3-tap convs, accumulate acts 1,3,5,7 into sum4
  for (int i = 0; i < 8; ++i) {
    const float* in = (i % 2 == 0) ? bufA : bufB;
    float* out = (i % 2 == 0) ? bufB : bufA;
    const float* wp = wt + (size_t)i * 196608;
    const float* bp = convs_b + i * 256;
    if (i == 1)
      gemm_k<1, 1, 0, 1, 1><<<dim3(64, 4), blk, 0, stream>>>(
          in, wp, bp, nullptr, out, sum4, M, 256, 768, 256, 1);
    else if (i == 3 || i == 5 || i == 7)
      gemm_k<1, 1, 0, 1, 2><<<dim3(64, 4), blk, 0, stream>>>(
          in, wp, bp, nullptr, out, sum4, M, 256, 768, 256, 1);
    else
      gemm_k<1, 1, 0, 1, 0><<<dim3(64, 4), blk, 0, stream>>>(
          in, wp, bp, nullptr, out, sum4, M, 256, 768, 256, 1);
  }

  // LN #1
  ln_kernel<<<4096, 64, 0, stream>>>(sum4, tln, ln_w, ln_b, 1e-5f);

  // QKV projections with (B,H,L,64) scatter
  gemm_k<0, 0, 0, 2, 0><<<dim3(64, 4), blk, 0, stream>>>(
      tln, wq, nullptr, nullptr, XQ, nullptr, M, 256, 256, 256, 0);
  gemm_k<0, 0, 0, 2, 0><<<dim3(64, 4), blk, 0, stream>>>(
      tln, wk, nullptr, nullptr, XK, nullptr, M, 256, 256, 256, 0);
  gemm_k<0, 0, 0, 2, 0><<<dim3(64, 4), blk, 0, stream>>>(
      tln, wv, nullptr, nullptr, XV, nullptr, M, 256, 256, 256, 0);

  // TTT scan: 16 chains
  ttt_kernel<<<16, blk, 0, stream>>>(XQ, XK, XV, ttt_W1, ttt_b1, ttt_W2, ttt_b2,
                                     ttt_lnw, ttt_lnb, tout);

  // x + out@wo  (residual = tln)
  gemm_k<0, 0, 1, 0, 0><<<dim3(64, 4), blk, 0, stream>>>(
      tout, wo, nullptr, tln, tfull, nullptr, M, 256, 256, 256, 0);

  // LN #2
  ln_kernel<<<4096, 64, 0, stream>>>(tfull, h2, ln_w, ln_b, 1e-5f);

  // fc (256->512), fc2 (512->64), fc3 (64->1)
  gemm_k<1, 0, 0, 0, 0><<<dim3(64, 8), blk, 0, stream>>>(
      h2, fc_w, fc_b, nullptr, f1, nullptr, M, 512, 256, 256, 0);
  gemm_k<1, 0, 0, 0, 0><<<dim3(64, 1), blk, 0, stream>>>(
      f1, fc2_w, fc2_b, nullptr, f2, nullptr, M, 64, 512, 512, 0);
  fc3_kernel<<<1024, blk, 0, stream>>>(f2, fc3_w, fc3_b, (float*)d_out);
}